// Round 7
// baseline (255.598 us; speedup 1.0000x reference)
//
#include <hip/hip_runtime.h>
#include <hip/hip_cooperative_groups.h>
namespace cg = cooperative_groups;

// B=4, H=W=128, D=64, NH=2, hd=32, 9 taps. All inputs fp32; compute fp16 MFMA.
// R7: single cooperative kernel, 256 blocks x 512 thr (1 block/CU), grid.sync()
// between stages: S0 prep (cvt+repack) -> S1 attn+ff1 -> S2 conv2 -> S3 conv3.
// Eliminates 3 launch gaps + prep dispatch; stage bodies = R6 logic.

typedef _Float16 half8 __attribute__((ext_vector_type(8)));
typedef _Float16 half4v __attribute__((ext_vector_type(4)));
typedef float f32x4 __attribute__((ext_vector_type(4)));

__device__ __forceinline__ f32x4 mfma16(half8 a, half8 b, f32x4 c) {
  return __builtin_amdgcn_mfma_f32_16x16x32_f16(a, b, c, 0, 0, 0);
}
__device__ __forceinline__ half8 ldfrag(const _Float16* p) { return *(const half8*)p; }
__device__ __forceinline__ half8 zfrag() { half8 z = {}; return z; }

__device__ __forceinline__ void gload_lds16(const _Float16* g, _Float16* l) {
  __builtin_amdgcn_global_load_lds(
      (const __attribute__((address_space(1))) void*)g,
      (__attribute__((address_space(3))) void*)l, 16, 0, 0);
}

// ---- 3x3 conv stage (full N per block): block = 2 rows, wave = 32 px ------
// LDS: 9*KB*NB frags (144) staged contiguously (matches wf order), 18/wave.
template <int KB, int NB, bool OUT_FP32>
__device__ __forceinline__ void conv_stage(
    _Float16* smem, const _Float16* __restrict__ in,
    const _Float16* __restrict__ wfrag, const float* __restrict__ bias,
    void* __restrict__ outp, int lane, int wid, int row, int rw) {
  const int l15 = lane & 15, q8 = (lane >> 4) * 8;
  const int p0 = row * 128 + rw * 32;
  const int h = row & 127;
  const int w0 = rw * 32;
  const int CIN = KB * 32, COUT = NB * 16;

#pragma unroll
  for (int i = 0; i < 18; ++i) {
    int f = wid * 18 + i;
    gload_lds16(wfrag + (size_t)f * 512 + lane * 8, smem + f * 512);
  }

  f32x4 acc[2][NB];
#pragma unroll
  for (int m = 0; m < 2; ++m)
#pragma unroll
    for (int nb = 0; nb < NB; ++nb) acc[m][nb] = f32x4{};

  half8 a[2][KB];
  {  // tap-0 prologue A-loads before the barrier (overlap staging)
    const bool rk = (unsigned)(h - 1) < 128u;
#pragma unroll
    for (int m = 0; m < 2; ++m) {
      const bool cv = rk && ((unsigned)(w0 + m * 16 + l15 - 1) < 128u);
      const _Float16* sp = in + (size_t)(p0 + m * 16 + l15 - 129) * CIN + q8;
#pragma unroll
      for (int kb = 0; kb < KB; ++kb) a[m][kb] = cv ? ldfrag(sp + kb * 32) : zfrag();
    }
  }

  __syncthreads();                          // staging complete

#pragma unroll
  for (int t = 0; t < 9; ++t) {
    const int dh = t / 3 - 1;
    const bool rowok = (unsigned)(h + dh) < 128u;
    half8 an[2][KB];
    if (t < 8) {                            // prefetch tap t+1 BEFORE compute
      const int dh2 = (t + 1) / 3 - 1, dw2 = (t + 1) % 3 - 1;
      const bool rk2 = (unsigned)(h + dh2) < 128u;
#pragma unroll
      for (int m = 0; m < 2; ++m) {
        const bool cv = rk2 && ((unsigned)(w0 + m * 16 + l15 + dw2) < 128u);
        const _Float16* sp = in + (size_t)(p0 + m * 16 + l15 + dh2 * 128 + dw2) * CIN + q8;
#pragma unroll
        for (int kb = 0; kb < KB; ++kb) an[m][kb] = cv ? ldfrag(sp + kb * 32) : zfrag();
      }
    }
    if (rowok) {
#pragma unroll
      for (int nb = 0; nb < NB; ++nb) {
#pragma unroll
        for (int kb = 0; kb < KB; ++kb) {
          half8 b = ldfrag(smem + (size_t)((t * KB + kb) * NB + nb) * 512 + lane * 8);
          acc[0][nb] = mfma16(a[0][kb], b, acc[0][nb]);
          acc[1][nb] = mfma16(a[1][kb], b, acc[1][nb]);
        }
      }
    }
    if (t < 8) {
#pragma unroll
      for (int m = 0; m < 2; ++m)
#pragma unroll
        for (int kb = 0; kb < KB; ++kb) a[m][kb] = an[m][kb];
    }
  }

#pragma unroll
  for (int m = 0; m < 2; ++m)
#pragma unroll
    for (int nb = 0; nb < NB; ++nb) {
      float bv = bias[nb * 16 + l15];
#pragma unroll
      for (int r = 0; r < 4; ++r) {
        float v = fmaxf(acc[m][nb][r] + bv, 0.f);
        size_t idx = (size_t)(p0 + m * 16 + (lane >> 4) * 4 + r) * COUT + nb * 16 + l15;
        if (OUT_FP32) ((float*)outp)[idx] = v;
        else          ((_Float16*)outp)[idx] = (_Float16)v;
      }
    }
}

// ---------------- the fused cooperative kernel -----------------------------
// wf frag layout (halves): AQ@0 AK@4096 BV@40960 B1@77824 BF2@81920 BF3@155648
__global__ __launch_bounds__(512) void fused(
    const float* __restrict__ x, const float* __restrict__ Kp,
    const float* __restrict__ Vp, const float* __restrict__ Qp,
    const float* __restrict__ W1, const float* __restrict__ f1b,
    const float* __restrict__ F2, const float* __restrict__ f2b,
    const float* __restrict__ F3, const float* __restrict__ f3b,
    _Float16* __restrict__ xh, _Float16* __restrict__ wf,
    _Float16* __restrict__ t1g, _Float16* __restrict__ t2g,
    float* __restrict__ outp) {
  extern __shared__ _Float16 smem[];
  const int lane = threadIdx.x & 63, wid = threadIdx.x >> 6;
  const int l15 = lane & 15, q8 = (lane >> 4) * 8;
  const int row = blockIdx.x * 2 + (wid >> 2);   // 2 rows per block
  const int rw = wid & 3;
  const int p0 = row * 128 + rw * 32;
  const int h = row & 127;
  const int w0 = rw * 32;
  const int gtid = blockIdx.x * 512 + threadIdx.x;  // 131072 threads

  // ======== S0: x -> fp16 (8 float4 each) + weight repack (2 elems each) ====
  {
    const float4* x4 = (const float4*)x;
#pragma unroll
    for (int k = 0; k < 8; ++k) {
      int i = gtid + k * 131072;
      float4 v = x4[i];
      half4v hv = { (_Float16)v.x, (_Float16)v.y, (_Float16)v.z, (_Float16)v.w };
      *(half4v*)(xh + (size_t)i * 4) = hv;
    }
#pragma unroll
    for (int k = 0; k < 2; ++k) {
      int e = gtid + k * 131072;
      if (e < 229376) {
        int j = e & 7, l = (e >> 3) & 63, f = e >> 9;
        int ll = l & 15, qq = (l >> 4) * 8;
        float v;
        if (f < 8)        { int mb = f >> 1, kb = f & 1;
                            v = Qp[(kb*32 + qq + j) * 64 + mb*16 + ll]; }
        else if (f < 80)  { int g = f - 8, t = g >> 3, mb = (g >> 1) & 3, kb = g & 1;
                            v = Kp[(kb*32 + qq + j) * 576 + t*64 + mb*16 + ll]; }
        else if (f < 152) { int g = f - 80, t = g >> 3, kb = (g >> 2) & 1, nb = g & 3;
                            v = Vp[(kb*32 + qq + j) * 576 + t*64 + nb*16 + ll]; }
        else if (f < 160) { int g = f - 152, kb = g >> 2, nb = g & 3;
                            v = W1[(kb*32 + qq + j) * 64 + nb*16 + ll]; }
        else if (f < 304) { int g = f - 160, t = g >> 4, kb = (g >> 3) & 1, nb = g & 7;
                            v = F2[(t*64 + kb*32 + qq + j) * 128 + nb*16 + ll]; }
        else              { int g = f - 304, t = g >> 4, kb = (g >> 2) & 3, nb = g & 3;
                            v = F3[(t*128 + kb*32 + qq + j) * 64 + nb*16 + ll]; }
        wf[e] = (_Float16)v;
      }
    }
  }
  cg::this_grid().sync();

  // ======== S1: attn + ff1 (R6 one-pass online softmax) =====================
  {
    float* dent = (float*)(smem + 77824) + wid * 64;

    // stage AK+BV+B1 (152 frags, 19/wave)
    {
      const _Float16* gw = wf + 4096 + (size_t)(wid * 19) * 512;
      _Float16* lw = smem + wid * 19 * 512;
      for (int i = 0; i < 19; ++i)
        gload_lds16(gw + i * 512 + lane * 8, lw + i * 512);
    }

    half8 ax0[2], ax1[2];
#pragma unroll
    for (int m = 0; m < 2; ++m) {
      const _Float16* xp = xh + (size_t)(p0 + m * 16 + l15) * 64 + q8;
      ax0[m] = ldfrag(xp); ax1[m] = ldfrag(xp + 32);
    }
    f32x4 qT[2][4];
#pragma unroll
    for (int cb = 0; cb < 4; ++cb) {
      half8 aq0 = ldfrag(wf + (cb * 2 + 0) * 512 + lane * 8);
      half8 aq1 = ldfrag(wf + (cb * 2 + 1) * 512 + lane * 8);
#pragma unroll
      for (int m = 0; m < 2; ++m) {
        f32x4 c = {};
        c = mfma16(aq0, ax0[m], c);
        c = mfma16(aq1, ax1[m], c);
        qT[m][cb] = c;
      }
    }

    auto load_tap = [&](int t, half8 (&x0)[2], half8 (&x1)[2]) {
      const int dh = t / 3 - 1, dw = t % 3 - 1;
      const bool rk = (unsigned)(h + dh) < 128u;
#pragma unroll
      for (int m = 0; m < 2; ++m) {
        const bool cv = rk && ((unsigned)(w0 + m * 16 + l15 + dw) < 128u);
        const _Float16* sp = xh + (size_t)(p0 + m * 16 + l15 + dh * 128 + dw) * 64 + q8;
        x0[m] = cv ? ldfrag(sp) : zfrag();
        x1[m] = cv ? ldfrag(sp + 32) : zfrag();
      }
    };

    float den0[2] = {0.f, 0.f}, den1[2] = {0.f, 0.f};
    auto score_tap = [&](int t, half8 (&x0)[2], half8 (&x1)[2],
                         float (&e0)[2], float (&e1)[2]) {
      const int dh = t / 3 - 1;
      const bool rowok = (unsigned)(h + dh) < 128u;
#pragma unroll
      for (int m = 0; m < 2; ++m) {
        float pa = 0.f, pb = 0.f;
        if (rowok) {
#pragma unroll
          for (int cb = 0; cb < 4; ++cb) {
            f32x4 c = {};
            c = mfma16(ldfrag(smem + (t * 8 + cb * 2 + 0) * 512 + lane * 8), x0[m], c);
            c = mfma16(ldfrag(smem + (t * 8 + cb * 2 + 1) * 512 + lane * 8), x1[m], c);
            float d = qT[m][cb].x * c.x + qT[m][cb].y * c.y
                    + qT[m][cb].z * c.z + qT[m][cb].w * c.w;
            if (cb < 2) pa += d; else pb += d;
          }
          pa += __shfl_xor(pa, 16, 64); pa += __shfl_xor(pa, 32, 64);
          pb += __shfl_xor(pb, 16, 64); pb += __shfl_xor(pb, 32, 64);
        }
        e0[m] = __expf(pa * (1.f / 3.f));
        e1[m] = __expf(pb * (1.f / 3.f));
        den0[m] += e0[m]; den1[m] += e1[m];
      }
    };

    half8 sx0[2], sx1[2];
    load_tap(0, sx0, sx1);

    __syncthreads();                        // staging complete

    float e0c[2], e1c[2];
    score_tap(0, sx0, sx1, e0c, e1c);

    const _Float16* BVl = smem + 36864;
    f32x4 at[2][4];
#pragma unroll
    for (int m = 0; m < 2; ++m)
#pragma unroll
      for (int nb = 0; nb < 4; ++nb) at[m][nb] = f32x4{};

#pragma unroll
    for (int t = 0; t < 9; ++t) {
      const bool rowok = (unsigned)(h + (t / 3 - 1)) < 128u;
      half8 nx0[2], nx1[2];
      if (t < 8) load_tap(t + 1, nx0, nx1);
      if (rowok) {
        half8 vf[8];
#pragma unroll
        for (int f = 0; f < 8; ++f) vf[f] = ldfrag(BVl + (t * 8 + f) * 512 + lane * 8);
#pragma unroll
        for (int m = 0; m < 2; ++m) {
          _Float16 h0 = (_Float16)e0c[m], h1 = (_Float16)e1c[m];
          half8 b0 = {h0, h0, h0, h0, h0, h0, h0, h0};
          half8 b1 = {h1, h1, h1, h1, h1, h1, h1, h1};
          half8 s00 = sx0[m] * b0, s01 = sx1[m] * b0;
          half8 s10 = sx0[m] * b1, s11 = sx1[m] * b1;
#pragma unroll
          for (int nb = 0; nb < 2; ++nb) {
            at[m][nb]     = mfma16(s00, vf[0 * 4 + nb],     at[m][nb]);
            at[m][nb]     = mfma16(s01, vf[1 * 4 + nb],     at[m][nb]);
            at[m][nb + 2] = mfma16(s10, vf[0 * 4 + nb + 2], at[m][nb + 2]);
            at[m][nb + 2] = mfma16(s11, vf[1 * 4 + nb + 2], at[m][nb + 2]);
          }
        }
      }
      if (t < 8) {
        float e0n[2], e1n[2];
        score_tap(t + 1, nx0, nx1, e0n, e1n);
#pragma unroll
        for (int m = 0; m < 2; ++m) {
          sx0[m] = nx0[m]; sx1[m] = nx1[m];
          e0c[m] = e0n[m]; e1c[m] = e1n[m];
        }
      }
    }

#pragma unroll
    for (int m = 0; m < 2; ++m) {
      dent[(m * 2 + 0) * 16 + l15] = den0[m];
      dent[(m * 2 + 1) * 16 + l15] = den1[m];
    }
    f32x4 iv[2][2];
#pragma unroll
    for (int m = 0; m < 2; ++m)
#pragma unroll
      for (int hd = 0; hd < 2; ++hd) {
        f32x4 dv = *(const f32x4*)(dent + (m * 2 + hd) * 16 + (lane >> 4) * 4);
        iv[m][hd] = f32x4{1.f / dv.x, 1.f / dv.y, 1.f / dv.z, 1.f / dv.w};
      }

    __syncthreads();                        // done with AK/BV; reuse for transpose
    _Float16* myt = smem + wid * 2304;
#pragma unroll
    for (int m = 0; m < 2; ++m)
#pragma unroll
      for (int nb = 0; nb < 4; ++nb) {
        const int hd = nb >> 1;
#pragma unroll
        for (int r = 0; r < 4; ++r)
          myt[m * 1152 + ((lane >> 4) * 4 + r) * 72 + nb * 16 + l15] =
              (_Float16)(at[m][nb][r] * iv[m][hd][r]);
      }
    const _Float16* B1l = smem + 73728;
#pragma unroll
    for (int m = 0; m < 2; ++m) {
      half8 aa0 = ldfrag(myt + m * 1152 + l15 * 72 + q8);
      half8 aa1 = ldfrag(myt + m * 1152 + l15 * 72 + 32 + q8);
#pragma unroll
      for (int nb = 0; nb < 4; ++nb) {
        f32x4 c = {};
        c = mfma16(aa0, ldfrag(B1l + (0 * 4 + nb) * 512 + lane * 8), c);
        c = mfma16(aa1, ldfrag(B1l + (1 * 4 + nb) * 512 + lane * 8), c);
        float bv = f1b[nb * 16 + l15];
#pragma unroll
        for (int r = 0; r < 4; ++r) {
          float v = fmaxf(c[r] + bv, 0.f);
          t1g[(size_t)(p0 + m * 16 + (lane >> 4) * 4 + r) * 64 + nb * 16 + l15] = (_Float16)v;
        }
      }
    }
  }
  cg::this_grid().sync();

  // ======== S2: conv2 (64 -> 128) ==========================================
  conv_stage<2, 8, false>(smem, t1g, wf + 81920, f2b, t2g, lane, wid, row, rw);
  cg::this_grid().sync();

  // ======== S3: conv3 (128 -> 64), fp32 out ================================
  conv_stage<4, 4, true>(smem, t2g, wf + 155648, f3b, outp, lane, wid, row, rw);
}

extern "C" void kernel_launch(void* const* d_in, const int* in_sizes, int n_in,
                              void* d_out, int out_size, void* d_ws, size_t ws_size,
                              hipStream_t stream) {
  (void)in_sizes; (void)n_in; (void)out_size; (void)ws_size;
  const float* x   = (const float*)d_in[0];
  const float* Kp  = (const float*)d_in[1];
  const float* Vp  = (const float*)d_in[2];
  const float* Qp  = (const float*)d_in[3];
  const float* f1w = (const float*)d_in[4];
  const float* f1b = (const float*)d_in[5];
  const float* f2w = (const float*)d_in[6];
  const float* f2b = (const float*)d_in[7];
  const float* f3w = (const float*)d_in[8];
  const float* f3b = (const float*)d_in[9];

  // ws layout (halves): xh[0,4194304) wf[4194304,4423680) t2[4423680,12812288)
  // t1[12812288,17006592)  = 34 MB total
  _Float16* xh  = (_Float16*)d_ws;
  _Float16* wf  = xh + 4194304;
  _Float16* t2g = wf + 229376;
  _Float16* t1g = t2g + 8388608;
  float* outp = (float*)d_out;

  (void)hipFuncSetAttribute((const void*)fused,
      hipFuncAttributeMaxDynamicSharedMemorySize, 157696);

  void* args[] = { (void*)&x, (void*)&Kp, (void*)&Vp, (void*)&Qp, (void*)&f1w,
                   (void*)&f1b, (void*)&f2w, (void*)&f2b, (void*)&f3w,
                   (void*)&f3b, (void*)&xh, (void*)&wf, (void*)&t1g,
                   (void*)&t2g, (void*)&outp };
  (void)hipLaunchCooperativeKernel((const void*)fused, dim3(256), dim3(512),
                                   args, 157696, stream);
}

// Round 8
// 147.244 us; speedup vs baseline: 1.7359x; 1.7359x over previous
//
#include <hip/hip_runtime.h>

// B=4, H=W=128, D=64, NH=2, hd=32, 9 taps. All inputs fp32; compute fp16 MFMA.
// R8: channel-octet-major activation layouts. xh/t1/t2 stored as planes
// [oct][pixel][8 halves] (oct = ch/8) so tap-loop A-fragment loads are
// quad-contiguous (8 cache lines/instr instead of 64 at pixel-major stride).
// Theory: R3-R7 were L2 line-throughput bound on strided 16B-per-lane loads.
// Stage bodies otherwise = R6 (one-pass online softmax attn, LDS weights).

typedef _Float16 half8 __attribute__((ext_vector_type(8)));
typedef float f32x4 __attribute__((ext_vector_type(4)));

#define PLANE 524288  // 65536 pixels x 8 halves per plane

__device__ __forceinline__ f32x4 mfma16(half8 a, half8 b, f32x4 c) {
  return __builtin_amdgcn_mfma_f32_16x16x32_f16(a, b, c, 0, 0, 0);
}
__device__ __forceinline__ half8 ldfrag(const _Float16* p) { return *(const half8*)p; }
__device__ __forceinline__ half8 zfrag() { half8 z = {}; return z; }

__device__ __forceinline__ void gload_lds16(const _Float16* g, _Float16* l) {
  __builtin_amdgcn_global_load_lds(
      (const __attribute__((address_space(1))) void*)g,
      (__attribute__((address_space(3))) void*)l, 16, 0, 0);
}

// ---------------- prep: x -> fp16 octet planes + weight repack -------------
// blocks [0,2048): plane cvt (thread = (oct,px)); [2048,2944): repack.
// Fragment = 64 lanes x 8 halves (1 KB). A-frag: A[m=l15][k=q8+j]. B: B[k][n=l15].
//   AQ  [mb4][kb2]      @ 0       AK  [t9][cb4][kb2]  @ 4096
//   BV  [t9][kb2][nb4]  @ 40960   B1  [kb2][nb4]      @ 77824
//   BF2 [t9][kb2][nb8]  @ 81920   BF3 [t9][kb4][nb4]  @ 155648  (229376 total)
__global__ __launch_bounds__(256) void prep(
    const float* __restrict__ x, const float* __restrict__ Kp,
    const float* __restrict__ Vp, const float* __restrict__ Qp,
    const float* __restrict__ W1, const float* __restrict__ F2,
    const float* __restrict__ F3, _Float16* __restrict__ xh,
    _Float16* __restrict__ out) {
  if (blockIdx.x < 2048) {
    int i = blockIdx.x * 256 + threadIdx.x;   // 524288 = 8 octs x 65536 px
    int oct = i >> 16, px = i & 65535;
    const float4* s = (const float4*)(x + (size_t)px * 64 + oct * 8);
    float4 a = s[0], b = s[1];
    half8 h = { (_Float16)a.x, (_Float16)a.y, (_Float16)a.z, (_Float16)a.w,
                (_Float16)b.x, (_Float16)b.y, (_Float16)b.z, (_Float16)b.w };
    *(half8*)(xh + (size_t)oct * PLANE + (size_t)px * 8) = h;
    return;
  }
  int e = (blockIdx.x - 2048) * 256 + threadIdx.x;  // 229376 total
  int j = e & 7, l = (e >> 3) & 63, f = e >> 9;
  int l15 = l & 15, q8 = (l >> 4) * 8;
  float v;
  if (f < 8)        { int mb = f >> 1, kb = f & 1;
                      v = Qp[(kb*32 + q8 + j) * 64 + mb*16 + l15]; }
  else if (f < 80)  { int g = f - 8, t = g >> 3, mb = (g >> 1) & 3, kb = g & 1;
                      v = Kp[(kb*32 + q8 + j) * 576 + t*64 + mb*16 + l15]; }
  else if (f < 152) { int g = f - 80, t = g >> 3, kb = (g >> 2) & 1, nb = g & 3;
                      v = Vp[(kb*32 + q8 + j) * 576 + t*64 + nb*16 + l15]; }
  else if (f < 160) { int g = f - 152, kb = g >> 2, nb = g & 3;
                      v = W1[(kb*32 + q8 + j) * 64 + nb*16 + l15]; }
  else if (f < 304) { int g = f - 160, t = g >> 4, kb = (g >> 3) & 1, nb = g & 7;
                      v = F2[(t*64 + kb*32 + q8 + j) * 128 + nb*16 + l15]; }
  else              { int g = f - 304, t = g >> 4, kb = (g >> 2) & 3, nb = g & 3;
                      v = F3[(t*128 + kb*32 + q8 + j) * 64 + nb*16 + l15]; }
  out[e] = (_Float16)v;
}

// ---------------- attention + ff1, one-pass online softmax -----------------
// 512 thr = 8 waves; block = 2 rows; wave = 32 px (m=2). LDS (halves):
// AK[0,36864) BV[36864,73728) B1[73728,77824) dentab(f32) @77824.
__global__ __launch_bounds__(512) void attn_ff1(
    const _Float16* __restrict__ xh, const _Float16* __restrict__ wf,
    const float* __restrict__ f1b, _Float16* __restrict__ t1g) {
  extern __shared__ _Float16 smem[];
  const int lane = threadIdx.x & 63, wid = threadIdx.x >> 6;
  const int l15 = lane & 15, q8 = (lane >> 4) * 8;
  const int row = blockIdx.x * 2 + (wid >> 2);
  const int rw = wid & 3;
  const int p0 = row * 128 + rw * 32;
  const int h = row & 127;
  const int w0 = rw * 32;
  const int oct0 = lane >> 4;               // x0 plane; x1 plane = oct0+4
  float* dent = (float*)(smem + 77824) + wid * 64;

  // stage AK+BV+B1 (152 frags, 19/wave); in flight during qT + prologue
  {
    const _Float16* gw = wf + 4096 + (size_t)(wid * 19) * 512;
    _Float16* lw = smem + wid * 19 * 512;
    for (int i = 0; i < 19; ++i)
      gload_lds16(gw + i * 512 + lane * 8, lw + i * 512);
  }

  // own-x fragments + q^T tiles
  half8 ax0[2], ax1[2];
#pragma unroll
  for (int m = 0; m < 2; ++m) {
    const size_t px = (size_t)(p0 + m * 16 + l15);
    ax0[m] = ldfrag(xh + (size_t)oct0 * PLANE + px * 8);
    ax1[m] = ldfrag(xh + (size_t)(oct0 + 4) * PLANE + px * 8);
  }
  f32x4 qT[2][4];
#pragma unroll
  for (int cb = 0; cb < 4; ++cb) {
    half8 aq0 = ldfrag(wf + (cb * 2 + 0) * 512 + lane * 8);
    half8 aq1 = ldfrag(wf + (cb * 2 + 1) * 512 + lane * 8);
#pragma unroll
    for (int m = 0; m < 2; ++m) {
      f32x4 c = {};
      c = mfma16(aq0, ax0[m], c);
      c = mfma16(aq1, ax1[m], c);
      qT[m][cb] = c;
    }
  }

  auto load_tap = [&](int t, half8 (&x0)[2], half8 (&x1)[2]) {
    const int dh = t / 3 - 1, dw = t % 3 - 1;
    const bool rk = (unsigned)(h + dh) < 128u;
#pragma unroll
    for (int m = 0; m < 2; ++m) {
      const bool cv = rk && ((unsigned)(w0 + m * 16 + l15 + dw) < 128u);
      const size_t px = (size_t)(p0 + m * 16 + l15 + dh * 128 + dw);
      x0[m] = cv ? ldfrag(xh + (size_t)oct0 * PLANE + px * 8) : zfrag();
      x1[m] = cv ? ldfrag(xh + (size_t)(oct0 + 4) * PLANE + px * 8) : zfrag();
    }
  };

  float den0[2] = {0.f, 0.f}, den1[2] = {0.f, 0.f};
  auto score_tap = [&](int t, half8 (&x0)[2], half8 (&x1)[2],
                       float (&e0)[2], float (&e1)[2]) {
    const int dh = t / 3 - 1;
    const bool rowok = (unsigned)(h + dh) < 128u;
#pragma unroll
    for (int m = 0; m < 2; ++m) {
      float pa = 0.f, pb = 0.f;
      if (rowok) {
#pragma unroll
        for (int cb = 0; cb < 4; ++cb) {
          f32x4 c = {};
          c = mfma16(ldfrag(smem + (t * 8 + cb * 2 + 0) * 512 + lane * 8), x0[m], c);
          c = mfma16(ldfrag(smem + (t * 8 + cb * 2 + 1) * 512 + lane * 8), x1[m], c);
          float d = qT[m][cb].x * c.x + qT[m][cb].y * c.y
                  + qT[m][cb].z * c.z + qT[m][cb].w * c.w;
          if (cb < 2) pa += d; else pb += d;
        }
        pa += __shfl_xor(pa, 16, 64); pa += __shfl_xor(pa, 32, 64);
        pb += __shfl_xor(pb, 16, 64); pb += __shfl_xor(pb, 32, 64);
      }
      e0[m] = __expf(pa * (1.f / 3.f));
      e1[m] = __expf(pb * (1.f / 3.f));
      den0[m] += e0[m]; den1[m] += e1[m];
    }
  };

  half8 sx0[2], sx1[2];
  load_tap(0, sx0, sx1);                    // tap-0 loads overlap staging drain

  __syncthreads();                          // staging complete

  float e0c[2], e1c[2];
  score_tap(0, sx0, sx1, e0c, e1c);

  const _Float16* BVl = smem + 36864;
  f32x4 at[2][4];
#pragma unroll
  for (int m = 0; m < 2; ++m)
#pragma unroll
    for (int nb = 0; nb < 4; ++nb) at[m][nb] = f32x4{};

#pragma unroll
  for (int t = 0; t < 9; ++t) {
    const bool rowok = (unsigned)(h + (t / 3 - 1)) < 128u;
    half8 nx0[2], nx1[2];
    if (t < 8) load_tap(t + 1, nx0, nx1);   // t+1 loads in flight
    if (rowok) {
      half8 vf[8];
#pragma unroll
      for (int f = 0; f < 8; ++f) vf[f] = ldfrag(BVl + (t * 8 + f) * 512 + lane * 8);
#pragma unroll
      for (int m = 0; m < 2; ++m) {
        _Float16 h0 = (_Float16)e0c[m], h1 = (_Float16)e1c[m];
        half8 b0 = {h0, h0, h0, h0, h0, h0, h0, h0};
        half8 b1 = {h1, h1, h1, h1, h1, h1, h1, h1};
        half8 s00 = sx0[m] * b0, s01 = sx1[m] * b0;
        half8 s10 = sx0[m] * b1, s11 = sx1[m] * b1;
#pragma unroll
        for (int nb = 0; nb < 2; ++nb) {
          at[m][nb]     = mfma16(s00, vf[0 * 4 + nb],     at[m][nb]);
          at[m][nb]     = mfma16(s01, vf[1 * 4 + nb],     at[m][nb]);
          at[m][nb + 2] = mfma16(s10, vf[0 * 4 + nb + 2], at[m][nb + 2]);
          at[m][nb + 2] = mfma16(s11, vf[1 * 4 + nb + 2], at[m][nb + 2]);
        }
      }
    }
    if (t < 8) {
      float e0n[2], e1n[2];
      score_tap(t + 1, nx0, nx1, e0n, e1n);
#pragma unroll
      for (int m = 0; m < 2; ++m) {
        sx0[m] = nx0[m]; sx1[m] = nx1[m];
        e0c[m] = e0n[m]; e1c[m] = e1n[m];
      }
    }
  }

  // per-pixel 1/den via per-wave LDS table
#pragma unroll
  for (int m = 0; m < 2; ++m) {
    dent[(m * 2 + 0) * 16 + l15] = den0[m];
    dent[(m * 2 + 1) * 16 + l15] = den1[m];
  }
  f32x4 iv[2][2];
#pragma unroll
  for (int m = 0; m < 2; ++m)
#pragma unroll
    for (int hd = 0; hd < 2; ++hd) {
      f32x4 dv = *(const f32x4*)(dent + (m * 2 + hd) * 16 + (lane >> 4) * 4);
      iv[m][hd] = f32x4{1.f / dv.x, 1.f / dv.y, 1.f / dv.z, 1.f / dv.w};
    }

  // -------- ff1: normalize + transpose -> GEMM -> channel-major scatter ----
  __syncthreads();                          // done reading AK/BV
  _Float16* myt = smem + wid * 2304;
#pragma unroll
  for (int m = 0; m < 2; ++m)
#pragma unroll
    for (int nb = 0; nb < 4; ++nb) {
      const int hd = nb >> 1;
#pragma unroll
      for (int r = 0; r < 4; ++r)
        myt[m * 1152 + ((lane >> 4) * 4 + r) * 72 + nb * 16 + l15] =
            (_Float16)(at[m][nb][r] * iv[m][hd][r]);
    }
  const _Float16* B1l = smem + 73728;
#pragma unroll
  for (int m = 0; m < 2; ++m) {
    half8 aa0 = ldfrag(myt + m * 1152 + l15 * 72 + q8);
    half8 aa1 = ldfrag(myt + m * 1152 + l15 * 72 + 32 + q8);
#pragma unroll
    for (int nb = 0; nb < 4; ++nb) {
      f32x4 c = {};
      c = mfma16(aa0, ldfrag(B1l + (0 * 4 + nb) * 512 + lane * 8), c);
      c = mfma16(aa1, ldfrag(B1l + (1 * 4 + nb) * 512 + lane * 8), c);
      float bv = f1b[nb * 16 + l15];
      const int ch = nb * 16 + l15;
      const size_t pbase = (size_t)(ch >> 3) * PLANE + (ch & 7);
#pragma unroll
      for (int r = 0; r < 4; ++r) {
        float v = fmaxf(c[r] + bv, 0.f);
        size_t px = (size_t)(p0 + m * 16 + (lane >> 4) * 4 + r);
        t1g[pbase + px * 8] = (_Float16)v;
      }
    }
  }
}

// ---------------- 3x3 conv, N-split, octet-plane I/O -----------------------
// Block = 2 rows x (COUT/2) channels; LDS 72 KB weights -> 2 blocks/CU.
// Input from [oct][px][8] planes; fp16 output scattered to planes; fp32
// output (final) written pixel-major.
template <int KB, int NBL, int COUT>
__global__ __launch_bounds__(512, 2) void conv3x3(
    const _Float16* __restrict__ in, const _Float16* __restrict__ wfrag,
    const float* __restrict__ bias, void* __restrict__ outp, int out_fp32) {
  extern __shared__ _Float16 smem[];
  const int lane = threadIdx.x & 63, wid = threadIdx.x >> 6;
  const int l15 = lane & 15, q8 = (lane >> 4) * 8;
  const int nh = blockIdx.x & 1;
  const int pairIdx = blockIdx.x >> 1;
  const int row = pairIdx * 2 + (wid >> 2);
  const int rw = wid & 3;
  const int p0 = row * 128 + rw * 32;
  const int h = row & 127;
  const int w0 = rw * 32;
  const int NBF = COUT / 16;
  const int oct0 = lane >> 4;

  {
    for (int s = 0; s < 9; ++s) {
      int f = wid * 9 + s;
      int t = f >> 3, r = f & 7, kb = r / NBL, i = r % NBL;
      const _Float16* g = wfrag + (size_t)((t * KB + kb) * NBF + nh * NBL + i) * 512;
      gload_lds16(g + lane * 8, smem + f * 512);
    }
  }

  f32x4 acc[2][NBL];
#pragma unroll
  for (int m = 0; m < 2; ++m)
#pragma unroll
    for (int nb = 0; nb < NBL; ++nb) acc[m][nb] = f32x4{};

  half8 a[2][KB];
  {  // tap-0 prologue A-loads before the barrier
    const bool rk = (unsigned)(h - 1) < 128u;
#pragma unroll
    for (int m = 0; m < 2; ++m) {
      const bool cv = rk && ((unsigned)(w0 + m * 16 + l15 - 1) < 128u);
      const size_t px = (size_t)(p0 + m * 16 + l15 - 129);
#pragma unroll
      for (int kb = 0; kb < KB; ++kb)
        a[m][kb] = cv ? ldfrag(in + (size_t)(kb * 4 + oct0) * PLANE + px * 8) : zfrag();
    }
  }

  __syncthreads();

#pragma unroll
  for (int t = 0; t < 9; ++t) {
    const int dh = t / 3 - 1;
    const bool rowok = (unsigned)(h + dh) < 128u;
    half8 an[2][KB];
    if (t < 8) {                            // prefetch tap t+1 BEFORE compute
      const int dh2 = (t + 1) / 3 - 1, dw2 = (t + 1) % 3 - 1;
      const bool rk2 = (unsigned)(h + dh2) < 128u;
#pragma unroll
      for (int m = 0; m < 2; ++m) {
        const bool cv = rk2 && ((unsigned)(w0 + m * 16 + l15 + dw2) < 128u);
        const size_t px = (size_t)(p0 + m * 16 + l15 + dh2 * 128 + dw2);
#pragma unroll
        for (int kb = 0; kb < KB; ++kb)
          an[m][kb] = cv ? ldfrag(in + (size_t)(kb * 4 + oct0) * PLANE + px * 8) : zfrag();
      }
    }
    if (rowok) {
#pragma unroll
      for (int nb = 0; nb < NBL; ++nb) {
#pragma unroll
        for (int kb = 0; kb < KB; ++kb) {
          half8 b = ldfrag(smem + (size_t)((t * KB + kb) * NBL + nb) * 512 + lane * 8);
          acc[0][nb] = mfma16(a[0][kb], b, acc[0][nb]);
          acc[1][nb] = mfma16(a[1][kb], b, acc[1][nb]);
        }
      }
    }
    if (t < 8) {
#pragma unroll
      for (int m = 0; m < 2; ++m)
#pragma unroll
        for (int kb = 0; kb < KB; ++kb) a[m][kb] = an[m][kb];
    }
  }

#pragma unroll
  for (int m = 0; m < 2; ++m)
#pragma unroll
    for (int nb = 0; nb < NBL; ++nb) {
      const int ch = nh * NBL * 16 + nb * 16 + l15;
      float bv = bias[ch];
#pragma unroll
      for (int r = 0; r < 4; ++r) {
        float v = fmaxf(acc[m][nb][r] + bv, 0.f);
        size_t px = (size_t)(p0 + m * 16 + (lane >> 4) * 4 + r);
        if (out_fp32) {
          ((float*)outp)[px * COUT + ch] = v;        // final: pixel-major fp32
        } else {
          ((_Float16*)outp)[(size_t)(ch >> 3) * PLANE + px * 8 + (ch & 7)] = (_Float16)v;
        }
      }
    }
}

extern "C" void kernel_launch(void* const* d_in, const int* in_sizes, int n_in,
                              void* d_out, int out_size, void* d_ws, size_t ws_size,
                              hipStream_t stream) {
  (void)in_sizes; (void)n_in; (void)out_size; (void)ws_size;
  const float* x   = (const float*)d_in[0];
  const float* Kp  = (const float*)d_in[1];
  const float* Vp  = (const float*)d_in[2];
  const float* Qp  = (const float*)d_in[3];
  const float* f1w = (const float*)d_in[4];
  const float* f1b = (const float*)d_in[5];
  const float* f2w = (const float*)d_in[6];
  const float* f2b = (const float*)d_in[7];
  const float* f3w = (const float*)d_in[8];
  const float* f3b = (const float*)d_in[9];

  // ws (halves): xh 8 planes [0,4194304) | wf [4194304,4423680)
  // | t1 8 planes [4423680,8617984) | t2 16 planes [8617984,17006592)  ~34 MB
  _Float16* xh  = (_Float16*)d_ws;
  _Float16* wf  = xh + 4194304;
  _Float16* t1g = wf + 229376;
  _Float16* t2g = t1g + 4194304;
  float* outp = (float*)d_out;

  (void)hipFuncSetAttribute((const void*)attn_ff1,
      hipFuncAttributeMaxDynamicSharedMemorySize, 157696);
  (void)hipFuncSetAttribute((const void*)conv3x3<2, 4, 128>,
      hipFuncAttributeMaxDynamicSharedMemorySize, 73728);
  (void)hipFuncSetAttribute((const void*)conv3x3<4, 2, 64>,
      hipFuncAttributeMaxDynamicSharedMemorySize, 73728);

  prep<<<2944, 256, 0, stream>>>(x, Kp, Vp, Qp, f1w, f2w, f3w, xh, wf);
  attn_ff1<<<256, 512, 157696, stream>>>(xh, wf, f1b, t1g);
  conv3x3<2, 4, 128><<<512, 512, 73728, stream>>>(t1g, wf + 81920, f2b, t2g, 0);
  conv3x3<4, 2, 64><<<512, 512, 73728, stream>>>(t2g, wf + 155648, f3b, outp, 1);
}

// Round 9
// 145.265 us; speedup vs baseline: 1.7595x; 1.0136x over previous
//
#include <hip/hip_runtime.h>

// B=4, H=W=128, D=64, NH=2, hd=32, 9 taps. All inputs fp32; compute fp16 MFMA.
// R9: consolidation. (1) prep reads x fully coalesced (thread = px-major,
// oct-minor; 64x32B contiguous per wave) instead of 256B-stride; (2) attn
// score path loads kf fragments once per tap (not per m). Rest = R8:
// octet-plane activations [oct][px][8], one-pass online-softmax attn,
// LDS-staged weights, N-split convs.

typedef _Float16 half8 __attribute__((ext_vector_type(8)));
typedef float f32x4 __attribute__((ext_vector_type(4)));

#define PLANE 524288  // 65536 pixels x 8 halves per plane

__device__ __forceinline__ f32x4 mfma16(half8 a, half8 b, f32x4 c) {
  return __builtin_amdgcn_mfma_f32_16x16x32_f16(a, b, c, 0, 0, 0);
}
__device__ __forceinline__ half8 ldfrag(const _Float16* p) { return *(const half8*)p; }
__device__ __forceinline__ half8 zfrag() { half8 z = {}; return z; }

__device__ __forceinline__ void gload_lds16(const _Float16* g, _Float16* l) {
  __builtin_amdgcn_global_load_lds(
      (const __attribute__((address_space(1))) void*)g,
      (__attribute__((address_space(3))) void*)l, 16, 0, 0);
}

// ---------------- prep: x -> fp16 octet planes + weight repack -------------
// blocks [0,2048): cvt, thread t -> px = b*32 + t/8, oct = t%8: lane reads
// 32 B contiguous (wave = 2 KB run), writes 16 B into plane (8x128B runs).
// blocks [2048,2944): weight repack (unchanged).
//   AQ  [mb4][kb2]      @ 0       AK  [t9][cb4][kb2]  @ 4096
//   BV  [t9][kb2][nb4]  @ 40960   B1  [kb2][nb4]      @ 77824
//   BF2 [t9][kb2][nb8]  @ 81920   BF3 [t9][kb4][nb4]  @ 155648  (229376 total)
__global__ __launch_bounds__(256) void prep(
    const float* __restrict__ x, const float* __restrict__ Kp,
    const float* __restrict__ Vp, const float* __restrict__ Qp,
    const float* __restrict__ W1, const float* __restrict__ F2,
    const float* __restrict__ F3, _Float16* __restrict__ xh,
    _Float16* __restrict__ out) {
  if (blockIdx.x < 2048) {
    const int t = threadIdx.x;
    const int px = blockIdx.x * 32 + (t >> 3);
    const int oct = t & 7;
    const float4* s = (const float4*)(x + (size_t)px * 64 + oct * 8);
    float4 a = s[0], b = s[1];
    half8 h = { (_Float16)a.x, (_Float16)a.y, (_Float16)a.z, (_Float16)a.w,
                (_Float16)b.x, (_Float16)b.y, (_Float16)b.z, (_Float16)b.w };
    *(half8*)(xh + (size_t)oct * PLANE + (size_t)px * 8) = h;
    return;
  }
  int e = (blockIdx.x - 2048) * 256 + threadIdx.x;  // 229376 total
  int j = e & 7, l = (e >> 3) & 63, f = e >> 9;
  int l15 = l & 15, q8 = (l >> 4) * 8;
  float v;
  if (f < 8)        { int mb = f >> 1, kb = f & 1;
                      v = Qp[(kb*32 + q8 + j) * 64 + mb*16 + l15]; }
  else if (f < 80)  { int g = f - 8, t = g >> 3, mb = (g >> 1) & 3, kb = g & 1;
                      v = Kp[(kb*32 + q8 + j) * 576 + t*64 + mb*16 + l15]; }
  else if (f < 152) { int g = f - 80, t = g >> 3, kb = (g >> 2) & 1, nb = g & 3;
                      v = Vp[(kb*32 + q8 + j) * 576 + t*64 + nb*16 + l15]; }
  else if (f < 160) { int g = f - 152, kb = g >> 2, nb = g & 3;
                      v = W1[(kb*32 + q8 + j) * 64 + nb*16 + l15]; }
  else if (f < 304) { int g = f - 160, t = g >> 4, kb = (g >> 3) & 1, nb = g & 7;
                      v = F2[(t*64 + kb*32 + q8 + j) * 128 + nb*16 + l15]; }
  else              { int g = f - 304, t = g >> 4, kb = (g >> 2) & 3, nb = g & 3;
                      v = F3[(t*128 + kb*32 + q8 + j) * 64 + nb*16 + l15]; }
  out[e] = (_Float16)v;
}

// ---------------- attention + ff1, one-pass online softmax -----------------
// 512 thr = 8 waves; block = 2 rows; wave = 32 px (m=2). LDS (halves):
// AK[0,36864) BV[36864,73728) B1[73728,77824) dentab(f32) @77824.
__global__ __launch_bounds__(512) void attn_ff1(
    const _Float16* __restrict__ xh, const _Float16* __restrict__ wf,
    const float* __restrict__ f1b, _Float16* __restrict__ t1g) {
  extern __shared__ _Float16 smem[];
  const int lane = threadIdx.x & 63, wid = threadIdx.x >> 6;
  const int l15 = lane & 15, q8 = (lane >> 4) * 8;
  const int row = blockIdx.x * 2 + (wid >> 2);
  const int rw = wid & 3;
  const int p0 = row * 128 + rw * 32;
  const int h = row & 127;
  const int w0 = rw * 32;
  const int oct0 = lane >> 4;               // x0 plane; x1 plane = oct0+4
  float* dent = (float*)(smem + 77824) + wid * 64;

  // stage AK+BV+B1 (152 frags, 19/wave); in flight during qT + prologue
  {
    const _Float16* gw = wf + 4096 + (size_t)(wid * 19) * 512;
    _Float16* lw = smem + wid * 19 * 512;
    for (int i = 0; i < 19; ++i)
      gload_lds16(gw + i * 512 + lane * 8, lw + i * 512);
  }

  // own-x fragments + q^T tiles
  half8 ax0[2], ax1[2];
#pragma unroll
  for (int m = 0; m < 2; ++m) {
    const size_t px = (size_t)(p0 + m * 16 + l15);
    ax0[m] = ldfrag(xh + (size_t)oct0 * PLANE + px * 8);
    ax1[m] = ldfrag(xh + (size_t)(oct0 + 4) * PLANE + px * 8);
  }
  f32x4 qT[2][4];
#pragma unroll
  for (int cb = 0; cb < 4; ++cb) {
    half8 aq0 = ldfrag(wf + (cb * 2 + 0) * 512 + lane * 8);
    half8 aq1 = ldfrag(wf + (cb * 2 + 1) * 512 + lane * 8);
#pragma unroll
    for (int m = 0; m < 2; ++m) {
      f32x4 c = {};
      c = mfma16(aq0, ax0[m], c);
      c = mfma16(aq1, ax1[m], c);
      qT[m][cb] = c;
    }
  }

  auto load_tap = [&](int t, half8 (&x0)[2], half8 (&x1)[2]) {
    const int dh = t / 3 - 1, dw = t % 3 - 1;
    const bool rk = (unsigned)(h + dh) < 128u;
#pragma unroll
    for (int m = 0; m < 2; ++m) {
      const bool cv = rk && ((unsigned)(w0 + m * 16 + l15 + dw) < 128u);
      const size_t px = (size_t)(p0 + m * 16 + l15 + dh * 128 + dw);
      x0[m] = cv ? ldfrag(xh + (size_t)oct0 * PLANE + px * 8) : zfrag();
      x1[m] = cv ? ldfrag(xh + (size_t)(oct0 + 4) * PLANE + px * 8) : zfrag();
    }
  };

  float den0[2] = {0.f, 0.f}, den1[2] = {0.f, 0.f};
  // kf fragments loaded ONCE per tap, shared across both m
  auto score_tap = [&](int t, half8 (&x0)[2], half8 (&x1)[2],
                       float (&e0)[2], float (&e1)[2]) {
    const int dh = t / 3 - 1;
    const bool rowok = (unsigned)(h + dh) < 128u;
    half8 kf[8];
    if (rowok) {
#pragma unroll
      for (int f = 0; f < 8; ++f)
        kf[f] = ldfrag(smem + (t * 8 + f) * 512 + lane * 8);
    }
#pragma unroll
    for (int m = 0; m < 2; ++m) {
      float pa = 0.f, pb = 0.f;
      if (rowok) {
#pragma unroll
        for (int cb = 0; cb < 4; ++cb) {
          f32x4 c = {};
          c = mfma16(kf[cb * 2 + 0], x0[m], c);
          c = mfma16(kf[cb * 2 + 1], x1[m], c);
          float d = qT[m][cb].x * c.x + qT[m][cb].y * c.y
                  + qT[m][cb].z * c.z + qT[m][cb].w * c.w;
          if (cb < 2) pa += d; else pb += d;
        }
        pa += __shfl_xor(pa, 16, 64); pa += __shfl_xor(pa, 32, 64);
        pb += __shfl_xor(pb, 16, 64); pb += __shfl_xor(pb, 32, 64);
      }
      e0[m] = __expf(pa * (1.f / 3.f));
      e1[m] = __expf(pb * (1.f / 3.f));
      den0[m] += e0[m]; den1[m] += e1[m];
    }
  };

  half8 sx0[2], sx1[2];
  load_tap(0, sx0, sx1);                    // tap-0 loads overlap staging drain

  __syncthreads();                          // staging complete

  float e0c[2], e1c[2];
  score_tap(0, sx0, sx1, e0c, e1c);

  const _Float16* BVl = smem + 36864;
  f32x4 at[2][4];
#pragma unroll
  for (int m = 0; m < 2; ++m)
#pragma unroll
    for (int nb = 0; nb < 4; ++nb) at[m][nb] = f32x4{};

#pragma unroll
  for (int t = 0; t < 9; ++t) {
    const bool rowok = (unsigned)(h + (t / 3 - 1)) < 128u;
    half8 nx0[2], nx1[2];
    if (t < 8) load_tap(t + 1, nx0, nx1);   // t+1 loads in flight
    if (rowok) {
      half8 vf[8];
#pragma unroll
      for (int f = 0; f < 8; ++f) vf[f] = ldfrag(BVl + (t * 8 + f) * 512 + lane * 8);
#pragma unroll
      for (int m = 0; m < 2; ++m) {
        _Float16 h0 = (_Float16)e0c[m], h1 = (_Float16)e1c[m];
        half8 b0 = {h0, h0, h0, h0, h0, h0, h0, h0};
        half8 b1 = {h1, h1, h1, h1, h1, h1, h1, h1};
        half8 s00 = sx0[m] * b0, s01 = sx1[m] * b0;
        half8 s10 = sx0[m] * b1, s11 = sx1[m] * b1;
#pragma unroll
        for (int nb = 0; nb < 2; ++nb) {
          at[m][nb]     = mfma16(s00, vf[0 * 4 + nb],     at[m][nb]);
          at[m][nb]     = mfma16(s01, vf[1 * 4 + nb],     at[m][nb]);
          at[m][nb + 2] = mfma16(s10, vf[0 * 4 + nb + 2], at[m][nb + 2]);
          at[m][nb + 2] = mfma16(s11, vf[1 * 4 + nb + 2], at[m][nb + 2]);
        }
      }
    }
    if (t < 8) {
      float e0n[2], e1n[2];
      score_tap(t + 1, nx0, nx1, e0n, e1n);
#pragma unroll
      for (int m = 0; m < 2; ++m) {
        sx0[m] = nx0[m]; sx1[m] = nx1[m];
        e0c[m] = e0n[m]; e1c[m] = e1n[m];
      }
    }
  }

  // per-pixel 1/den via per-wave LDS table
#pragma unroll
  for (int m = 0; m < 2; ++m) {
    dent[(m * 2 + 0) * 16 + l15] = den0[m];
    dent[(m * 2 + 1) * 16 + l15] = den1[m];
  }
  f32x4 iv[2][2];
#pragma unroll
  for (int m = 0; m < 2; ++m)
#pragma unroll
    for (int hd = 0; hd < 2; ++hd) {
      f32x4 dv = *(const f32x4*)(dent + (m * 2 + hd) * 16 + (lane >> 4) * 4);
      iv[m][hd] = f32x4{1.f / dv.x, 1.f / dv.y, 1.f / dv.z, 1.f / dv.w};
    }

  // -------- ff1: normalize + transpose -> GEMM -> channel-major scatter ----
  __syncthreads();                          // done reading AK/BV
  _Float16* myt = smem + wid * 2304;
#pragma unroll
  for (int m = 0; m < 2; ++m)
#pragma unroll
    for (int nb = 0; nb < 4; ++nb) {
      const int hd = nb >> 1;
#pragma unroll
      for (int r = 0; r < 4; ++r)
        myt[m * 1152 + ((lane >> 4) * 4 + r) * 72 + nb * 16 + l15] =
            (_Float16)(at[m][nb][r] * iv[m][hd][r]);
    }
  const _Float16* B1l = smem + 73728;
#pragma unroll
  for (int m = 0; m < 2; ++m) {
    half8 aa0 = ldfrag(myt + m * 1152 + l15 * 72 + q8);
    half8 aa1 = ldfrag(myt + m * 1152 + l15 * 72 + 32 + q8);
#pragma unroll
    for (int nb = 0; nb < 4; ++nb) {
      f32x4 c = {};
      c = mfma16(aa0, ldfrag(B1l + (0 * 4 + nb) * 512 + lane * 8), c);
      c = mfma16(aa1, ldfrag(B1l + (1 * 4 + nb) * 512 + lane * 8), c);
      float bv = f1b[nb * 16 + l15];
      const int ch = nb * 16 + l15;
      const size_t pbase = (size_t)(ch >> 3) * PLANE + (ch & 7);
#pragma unroll
      for (int r = 0; r < 4; ++r) {
        float v = fmaxf(c[r] + bv, 0.f);
        size_t px = (size_t)(p0 + m * 16 + (lane >> 4) * 4 + r);
        t1g[pbase + px * 8] = (_Float16)v;
      }
    }
  }
}

// ---------------- 3x3 conv, N-split, octet-plane I/O -----------------------
// Block = 2 rows x (COUT/2) channels; LDS 72 KB weights -> 2 blocks/CU.
template <int KB, int NBL, int COUT>
__global__ __launch_bounds__(512, 2) void conv3x3(
    const _Float16* __restrict__ in, const _Float16* __restrict__ wfrag,
    const float* __restrict__ bias, void* __restrict__ outp, int out_fp32) {
  extern __shared__ _Float16 smem[];
  const int lane = threadIdx.x & 63, wid = threadIdx.x >> 6;
  const int l15 = lane & 15;
  const int nh = blockIdx.x & 1;
  const int pairIdx = blockIdx.x >> 1;
  const int row = pairIdx * 2 + (wid >> 2);
  const int rw = wid & 3;
  const int p0 = row * 128 + rw * 32;
  const int h = row & 127;
  const int w0 = rw * 32;
  const int NBF = COUT / 16;
  const int oct0 = lane >> 4;

  {
    for (int s = 0; s < 9; ++s) {
      int f = wid * 9 + s;
      int t = f >> 3, r = f & 7, kb = r / NBL, i = r % NBL;
      const _Float16* g = wfrag + (size_t)((t * KB + kb) * NBF + nh * NBL + i) * 512;
      gload_lds16(g + lane * 8, smem + f * 512);
    }
  }

  f32x4 acc[2][NBL];
#pragma unroll
  for (int m = 0; m < 2; ++m)
#pragma unroll
    for (int nb = 0; nb < NBL; ++nb) acc[m][nb] = f32x4{};

  half8 a[2][KB];
  {  // tap-0 prologue A-loads before the barrier
    const bool rk = (unsigned)(h - 1) < 128u;
#pragma unroll
    for (int m = 0; m < 2; ++m) {
      const bool cv = rk && ((unsigned)(w0 + m * 16 + l15 - 1) < 128u);
      const size_t px = (size_t)(p0 + m * 16 + l15 - 129);
#pragma unroll
      for (int kb = 0; kb < KB; ++kb)
        a[m][kb] = cv ? ldfrag(in + (size_t)(kb * 4 + oct0) * PLANE + px * 8) : zfrag();
    }
  }

  __syncthreads();

#pragma unroll
  for (int t = 0; t < 9; ++t) {
    const int dh = t / 3 - 1;
    const bool rowok = (unsigned)(h + dh) < 128u;
    half8 an[2][KB];
    if (t < 8) {                            // prefetch tap t+1 BEFORE compute
      const int dh2 = (t + 1) / 3 - 1, dw2 = (t + 1) % 3 - 1;
      const bool rk2 = (unsigned)(h + dh2) < 128u;
#pragma unroll
      for (int m = 0; m < 2; ++m) {
        const bool cv = rk2 && ((unsigned)(w0 + m * 16 + l15 + dw2) < 128u);
        const size_t px = (size_t)(p0 + m * 16 + l15 + dh2 * 128 + dw2);
#pragma unroll
        for (int kb = 0; kb < KB; ++kb)
          an[m][kb] = cv ? ldfrag(in + (size_t)(kb * 4 + oct0) * PLANE + px * 8) : zfrag();
      }
    }
    if (rowok) {
#pragma unroll
      for (int nb = 0; nb < NBL; ++nb) {
#pragma unroll
        for (int kb = 0; kb < KB; ++kb) {
          half8 b = ldfrag(smem + (size_t)((t * KB + kb) * NBL + nb) * 512 + lane * 8);
          acc[0][nb] = mfma16(a[0][kb], b, acc[0][nb]);
          acc[1][nb] = mfma16(a[1][kb], b, acc[1][nb]);
        }
      }
    }
    if (t < 8) {
#pragma unroll
      for (int m = 0; m < 2; ++m)
#pragma unroll
        for (int kb = 0; kb < KB; ++kb) a[m][kb] = an[m][kb];
    }
  }

#pragma unroll
  for (int m = 0; m < 2; ++m)
#pragma unroll
    for (int nb = 0; nb < NBL; ++nb) {
      const int ch = nh * NBL * 16 + nb * 16 + l15;
      float bv = bias[ch];
#pragma unroll
      for (int r = 0; r < 4; ++r) {
        float v = fmaxf(acc[m][nb][r] + bv, 0.f);
        size_t px = (size_t)(p0 + m * 16 + (lane >> 4) * 4 + r);
        if (out_fp32) {
          ((float*)outp)[px * COUT + ch] = v;        // final: pixel-major fp32
        } else {
          ((_Float16*)outp)[(size_t)(ch >> 3) * PLANE + px * 8 + (ch & 7)] = (_Float16)v;
        }
      }
    }
}

extern "C" void kernel_launch(void* const* d_in, const int* in_sizes, int n_in,
                              void* d_out, int out_size, void* d_ws, size_t ws_size,
                              hipStream_t stream) {
  (void)in_sizes; (void)n_in; (void)out_size; (void)ws_size;
  const float* x   = (const float*)d_in[0];
  const float* Kp  = (const float*)d_in[1];
  const float* Vp  = (const float*)d_in[2];
  const float* Qp  = (const float*)d_in[3];
  const float* f1w = (const float*)d_in[4];
  const float* f1b = (const float*)d_in[5];
  const float* f2w = (const float*)d_in[6];
  const float* f2b = (const float*)d_in[7];
  const float* f3w = (const float*)d_in[8];
  const float* f3b = (const float*)d_in[9];

  // ws (halves): xh 8 planes [0,4194304) | wf [4194304,4423680)
  // | t1 8 planes [4423680,8617984) | t2 16 planes [8617984,17006592)  ~34 MB
  _Float16* xh  = (_Float16*)d_ws;
  _Float16* wf  = xh + 4194304;
  _Float16* t1g = wf + 229376;
  _Float16* t2g = t1g + 4194304;
  float* outp = (float*)d_out;

  (void)hipFuncSetAttribute((const void*)attn_ff1,
      hipFuncAttributeMaxDynamicSharedMemorySize, 157696);
  (void)hipFuncSetAttribute((const void*)conv3x3<2, 4, 128>,
      hipFuncAttributeMaxDynamicSharedMemorySize, 73728);
  (void)hipFuncSetAttribute((const void*)conv3x3<4, 2, 64>,
      hipFuncAttributeMaxDynamicSharedMemorySize, 73728);

  prep<<<2944, 256, 0, stream>>>(x, Kp, Vp, Qp, f1w, f2w, f3w, xh, wf);
  attn_ff1<<<256, 512, 157696, stream>>>(xh, wf, f1b, t1g);
  conv3x3<2, 4, 128><<<512, 512, 73728, stream>>>(t1g, wf + 81920, f2b, t2g, 0);
  conv3x3<4, 2, 64><<<512, 512, 73728, stream>>>(t2g, wf + 155648, f3b, outp, 1);
}